// Round 3
// baseline (7262.073 us; speedup 1.0000x reference)
//
#include <hip/hip_runtime.h>
#include <stdint.h>

#define DI __device__ __forceinline__

typedef _Float16 f16x8 __attribute__((ext_vector_type(8)));
typedef float f32x4 __attribute__((ext_vector_type(4)));
typedef unsigned long long u64;
typedef unsigned short u16;

// ---- problem constants ----
constexpr int kB = 4;
constexpr int kN = 65536;
constexpr int kG = 512;   // NUM_GROUP
constexpr int kM = 64;    // GROUP_SIZE
constexpr int kE = 60;    // EMB
constexpr int GRD = 20;   // KNN grid resolution
constexpr int NCELL = GRD * GRD * GRD;
constexpr float CW = 1.0f / 20.0f;

constexpr int NCH = 2048;   // FPS chunks per batch
constexpr int CHSZ = 32;    // points per chunk
constexpr int NFPS = kB;    // one FPS block per batch
constexpr int NWORK = 508;
constexpr int NBLK = NFPS + NWORK;   // 512 blocks, 2/CU

// ---- workspace layout (bytes) ----
// cline: per-(b,it) center publication, 128B stride (1 writer, 1 reader):
//   word k (k=0,1,2) = (coord_bits<<32) | (it+1)
constexpr size_t OFF_CLINE  = 0;
constexpr size_t OFF_GRDY   = (size_t)kB * kG * 128;             // 4 u32 ready flags
constexpr size_t ZERO_BYTES = OFF_GRDY + 64;
constexpr size_t OFF_CSTART = (ZERO_BYTES + 255) & ~(size_t)255; // kB*(NCELL+1) u32
constexpr size_t OFF_DD     = (OFF_CSTART + (size_t)kB * (NCELL + 1) * 4 + 255) & ~(size_t)255;
constexpr size_t OFF_SW1    = (OFF_DD + (size_t)kB * kN * 4 + 255) & ~(size_t)255;
constexpr size_t OFF_SW2    = OFF_SW1 + 2048 * 2;
constexpr size_t OFF_SW3    = OFF_SW2 + 8192 * 2;
constexpr size_t OFF_SW4    = OFF_SW3 + 32768 * 2;
constexpr size_t OFF_WPT    = OFF_SW4 + 131072 * 2;
constexpr size_t OFF_SORT   = ((OFF_WPT + 60 * 512 * 4) + 255) & ~(size_t)255; // kB*kN float4

DI int cellof(float x) {
  int c = (int)(x * (float)GRD);
  return min(GRD - 1, max(0, c));
}
DI unsigned orderable(float f) {
  unsigned u = __float_as_uint(f);
  return (u & 0x80000000u) ? ~u : (u | 0x80000000u);
}
DI _Float16 f16dn(float v) {   // round toward -inf (v >= 0)
  _Float16 h = (_Float16)v;
  if ((float)h > v) h = __builtin_bit_cast(_Float16, (u16)(__builtin_bit_cast(u16, h) - 1));
  return h;
}
DI _Float16 f16up(float v) {   // round toward +inf (v in [0,1))
  _Float16 h = (_Float16)v;
  if ((float)h < v) h = __builtin_bit_cast(_Float16, (u16)(__builtin_bit_cast(u16, h) + 1));
  return h;
}

// =====================  zero the sync region  =====================
__global__ void k_zero(uint32_t* p, int nwords) {
  int i = blockIdx.x * blockDim.x + threadIdx.x;
  int st = gridDim.x * blockDim.x;
  for (; i < nwords; i += st) p[i] = 0u;
}

// =====================  weight prep (unchanged)  =====================
DI void swz(const float* __restrict__ W, _Float16* __restrict__ sw,
            int total, int nks, int Kreal, int N, int i0, int st) {
  for (int i = i0; i < total; i += st) {
    int j = i & 7, lane = (i >> 3) & 63, rest = i >> 9;
    int ks = rest % nks, nt = rest / nks;
    int k = ks * 32 + ((lane >> 4) << 3) + j;
    int n = nt * 16 + (lane & 15);
    sw[i] = (_Float16)((k < Kreal) ? W[k * N + n] : 0.f);
  }
}

__global__ void k_prep(const float* __restrict__ W1, const float* __restrict__ W2,
                       const float* __restrict__ W3, const float* __restrict__ W4,
                       const float* __restrict__ Wp,
                       _Float16* __restrict__ sw1, _Float16* __restrict__ sw2,
                       _Float16* __restrict__ sw3, _Float16* __restrict__ sw4,
                       float* __restrict__ wpt) {
  int i0 = blockIdx.x * blockDim.x + threadIdx.x;
  int st = gridDim.x * blockDim.x;
  swz(W1, sw1, 2048, 1, 6, 64, i0, st);
  swz(W2, sw2, 8192, 2, 64, 128, i0, st);
  swz(W3, sw3, 32768, 4, 128, 256, i0, st);
  swz(W4, sw4, 131072, 8, 256, 512, i0, st);
  for (int i = i0; i < 60 * 512; i += st) { int n = i >> 9, k = i & 511; wpt[i] = Wp[k * 60 + n]; }
}

// =====================  bitonic sort (shared, 256 threads)  =====================
DI void bitonic(u64* a, int n, int tid) {
  for (int k = 2; k <= n; k <<= 1)
    for (int j = k >> 1; j > 0; j >>= 1) {
      __syncthreads();
      for (int i = tid; i < n; i += 256) {
        int ix = i ^ j;
        if (ix > i) {
          u64 x = a[i], y = a[ix];
          bool up = ((i & k) == 0);
          if ((x > y) == up) { a[i] = y; a[ix] = x; }
        }
      }
    }
  __syncthreads();
}

// =====================  MLP layers (f16 MFMA, unchanged)  =====================
template <int Kdim, int Ndim, int SIN, int SOUT>
DI void mfma_layer(const _Float16* __restrict__ Xin, _Float16* __restrict__ Xout,
                   const _Float16* __restrict__ Wsw, const float* __restrict__ bias,
                   int wave, int lane) {
  constexpr int NKS = Kdim / 32;
  constexpr int NTW = Ndim / 64;
  constexpr int CH = (NTW < 4) ? NTW : 4;
  const int quad = lane >> 4, l16 = lane & 15;
  for (int c0 = 0; c0 < NTW; c0 += CH) {
    f32x4 acc[CH][4];
#pragma unroll
    for (int nt = 0; nt < CH; ++nt) {
      float bv = bias[wave * (Ndim / 4) + (c0 + nt) * 16 + l16];
#pragma unroll
      for (int m = 0; m < 4; ++m) acc[nt][m] = {bv, bv, bv, bv};
    }
#pragma unroll
    for (int ks = 0; ks < NKS; ++ks) {
      f16x8 af[4];
#pragma unroll
      for (int m = 0; m < 4; ++m)
        af[m] = *(const f16x8*)(Xin + (m * 16 + l16) * SIN + ks * 32 + quad * 8);
#pragma unroll
      for (int nt = 0; nt < CH; ++nt) {
        int ntg = wave * NTW + c0 + nt;
        f16x8 bf = *(const f16x8*)(Wsw + ((size_t)(ntg * NKS + ks) * 64 + lane) * 8);
#pragma unroll
        for (int m = 0; m < 4; ++m)
          acc[nt][m] = __builtin_amdgcn_mfma_f32_16x16x32_f16(af[m], bf, acc[nt][m], 0, 0, 0);
      }
    }
#pragma unroll
    for (int nt = 0; nt < CH; ++nt) {
      int col = wave * (Ndim / 4) + (c0 + nt) * 16 + l16;
#pragma unroll
      for (int m = 0; m < 4; ++m)
#pragma unroll
        for (int r = 0; r < 4; ++r) {
          int row = m * 16 + quad * 4 + r;
          Xout[row * SOUT + col] = (_Float16)fmaxf(acc[nt][m][r], 0.f);
        }
    }
  }
}

DI void mfma_layer4(const _Float16* __restrict__ Xin, const _Float16* __restrict__ Wsw,
                    const float* __restrict__ bias, float* __restrict__ maxv,
                    int wave, int lane) {
  constexpr int SIN = 264, NKS = 8, NTW = 8, CH = 4;
  const int quad = lane >> 4, l16 = lane & 15;
  for (int c0 = 0; c0 < NTW; c0 += CH) {
    f32x4 acc[CH][4];
#pragma unroll
    for (int nt = 0; nt < CH; ++nt) {
      float bv = bias[wave * 128 + (c0 + nt) * 16 + l16];
#pragma unroll
      for (int m = 0; m < 4; ++m) acc[nt][m] = {bv, bv, bv, bv};
    }
#pragma unroll
    for (int ks = 0; ks < NKS; ++ks) {
      f16x8 af[4];
#pragma unroll
      for (int m = 0; m < 4; ++m)
        af[m] = *(const f16x8*)(Xin + (m * 16 + l16) * SIN + ks * 32 + quad * 8);
#pragma unroll
      for (int nt = 0; nt < CH; ++nt) {
        int ntg = wave * NTW + c0 + nt;
        f16x8 bf = *(const f16x8*)(Wsw + ((size_t)(ntg * NKS + ks) * 64 + lane) * 8);
#pragma unroll
        for (int m = 0; m < 4; ++m)
          acc[nt][m] = __builtin_amdgcn_mfma_f32_16x16x32_f16(af[m], bf, acc[nt][m], 0, 0, 0);
      }
    }
#pragma unroll
    for (int nt = 0; nt < CH; ++nt) {
      float mx = 0.f;  // relu folded into max
#pragma unroll
      for (int m = 0; m < 4; ++m)
#pragma unroll
        for (int r = 0; r < 4; ++r) mx = fmaxf(mx, acc[nt][m][r]);
      mx = fmaxf(mx, __shfl_xor(mx, 16, 64));
      mx = fmaxf(mx, __shfl_xor(mx, 32, 64));
      if (quad == 0) maxv[wave * 128 + (c0 + nt) * 16 + l16] = mx;
    }
  }
}

// =====================  FPS: single block per batch, bound-skip chunks  ===========
// LDS layout (fps path), unioned with worker smem:
//   [0,16384)       ckey u64[2048]   exact per-chunk (maxdd | ~origidx)
//   [16384,40960)   cxyz float[2048][3]  coords of chunk's best point
//   [40960,65536)   cbb  f16[2048][6]    outward bbox {lox,hix,loy,hiy,loz,hiz}
//   [65536,69632)   queue u16[2048]
//   [69632,69760)   misc: qn, warr_key[4], warr_cid[4], wslot(float4)
// build-phase union: ccnt u32[8192] @0, cur u32[8192] @32768, spart u32[256] @65536
DI void fps_block(const float* __restrict__ xyz, float* __restrict__ outC,
                  u64* __restrict__ cline, uint32_t* __restrict__ grdy,
                  uint32_t* __restrict__ cstart_g, float4* __restrict__ sorted_g,
                  float* __restrict__ dd_g, int b, char* smem) {
  __builtin_amdgcn_s_setprio(3);
  const int tid = threadIdx.x;
  const int wave = tid >> 6, lane = tid & 63;
  const int h = tid >> 5, sub = tid & 31;          // half-wave id 0..7
  const float* X = xyz + (size_t)b * kN * 3;
  float4* SP = sorted_g + (size_t)b * kN;
  float* DD = dd_g + (size_t)b * kN;
  u64* cl = cline + (size_t)b * kG * 16;

  u64* ckey = (u64*)smem;
  float* cxyz = (float*)(smem + 16384);
  _Float16* cbb = (_Float16*)(smem + 40960);
  u16* queue = (u16*)(smem + 65536);
  int* qn = (int*)(smem + 69632);
  u64* warr_key = (u64*)(smem + 69640);
  int* warr_cid = (int*)(smem + 69672);
  float4* wslot = (float4*)(smem + 69696);

  // ---- build: count -> scan -> scatter -> bbox ----
  {
    uint32_t* ccnt = (uint32_t*)smem;
    uint32_t* cur = (uint32_t*)(smem + 32768);
    uint32_t* spart = (uint32_t*)(smem + 65536);
    for (int i = tid; i < 8192; i += 256) ccnt[i] = 0u;
    __syncthreads();
    for (int i = tid; i < kN; i += 256) {
      float x = X[3 * i], y = X[3 * i + 1], z = X[3 * i + 2];
      int cid = (cellof(z) * GRD + cellof(y)) * GRD + cellof(x);
      atomicAdd(&ccnt[cid], 1u);
    }
    __syncthreads();
    uint32_t* cs = cstart_g + (size_t)b * (NCELL + 1);
    const int chunk = 32;
    int c0 = tid * chunk;
    uint32_t s = 0;
    for (int i = 0; i < chunk; ++i) s += ccnt[c0 + i];
    spart[tid] = s;
    __syncthreads();
    for (int off = 1; off < 256; off <<= 1) {
      uint32_t add = (tid >= off) ? spart[tid - off] : 0u;
      __syncthreads();
      spart[tid] += add;
      __syncthreads();
    }
    uint32_t run = spart[tid] - s;
    for (int i = 0; i < chunk; ++i) {
      int c = c0 + i;
      uint32_t cc = ccnt[c];
      cur[c] = run;
      if (c < NCELL) cs[c] = run;
      run += cc;
    }
    if (tid == 255) cs[NCELL] = run;
    __syncthreads();
    for (int i = tid; i < kN; i += 256) {
      float x = X[3 * i], y = X[3 * i + 1], z = X[3 * i + 2];
      int cid = (cellof(z) * GRD + cellof(y)) * GRD + cellof(x);
      uint32_t pos = atomicAdd(&cur[cid], 1u);
      SP[pos] = make_float4(x, y, z, __uint_as_float((unsigned)i));
    }
    __syncthreads();   // includes vmcnt(0): sorted[] complete in L2
    // bbox per chunk, half-wave cooperative
    for (int c = h; c < NCH; c += 8) {
      float4 p = SP[c * CHSZ + sub];
      float mnx = p.x, mxx = p.x, mny = p.y, mxy = p.y, mnz = p.z, mxz = p.z;
#pragma unroll
      for (int off = 16; off; off >>= 1) {
        mnx = fminf(mnx, __shfl_down(mnx, (unsigned)off));
        mxx = fmaxf(mxx, __shfl_down(mxx, (unsigned)off));
        mny = fminf(mny, __shfl_down(mny, (unsigned)off));
        mxy = fmaxf(mxy, __shfl_down(mxy, (unsigned)off));
        mnz = fminf(mnz, __shfl_down(mnz, (unsigned)off));
        mxz = fmaxf(mxz, __shfl_down(mxz, (unsigned)off));
      }
      if (sub == 0) {
        cbb[c * 6 + 0] = f16dn(mnx); cbb[c * 6 + 1] = f16up(mxx);
        cbb[c * 6 + 2] = f16dn(mny); cbb[c * 6 + 3] = f16up(mxy);
        cbb[c * 6 + 4] = f16dn(mnz); cbb[c * 6 + 5] = f16up(mxz);
      }
    }
    __syncthreads();
  }
  // flush grid data to coherence point, then signal ready + publish center 0
  __threadfence();
  __syncthreads();
  float cx = X[0], cy = X[1], cz = X[2];
  if (tid == 0) {
    __hip_atomic_store(grdy + b, 1u, __ATOMIC_RELEASE, __HIP_MEMORY_SCOPE_AGENT);
    u64 tg = 1u;
    __hip_atomic_store(cl + 0, ((u64)__float_as_uint(cx) << 32) | tg, __ATOMIC_RELAXED, __HIP_MEMORY_SCOPE_AGENT);
    __hip_atomic_store(cl + 1, ((u64)__float_as_uint(cy) << 32) | tg, __ATOMIC_RELAXED, __HIP_MEMORY_SCOPE_AGENT);
    __hip_atomic_store(cl + 2, ((u64)__float_as_uint(cz) << 32) | tg, __ATOMIC_RELAXED, __HIP_MEMORY_SCOPE_AGENT);
    outC[(size_t)b * kG * 3 + 0] = cx;
    outC[(size_t)b * kG * 3 + 1] = cy;
    outC[(size_t)b * kG * 3 + 2] = cz;
    *qn = 0;
  }
  __syncthreads();

  // ---- rounds ----
  for (int it = 1; it < kG; ++it) {
    // Phase A: bound tests -> queue (skip for it==1: refine all)
    if (it > 1) {
#pragma unroll
      for (int i = 0; i < 8; ++i) {
        int c = tid + 256 * i;
        int c6 = c * 6;
        float lox = (float)cbb[c6 + 0], hix = (float)cbb[c6 + 1];
        float loy = (float)cbb[c6 + 2], hiy = (float)cbb[c6 + 3];
        float loz = (float)cbb[c6 + 4], hiz = (float)cbb[c6 + 5];
        float dx = fmaxf(fmaxf(lox - cx, cx - hix), 0.f);
        float dy = fmaxf(fmaxf(loy - cy, cy - hiy), 0.f);
        float dz = fmaxf(fmaxf(loz - cz, cz - hiz), 0.f);
        float lb = dx * dx + dy * dy + dz * dz;
        float ub = __uint_as_float((unsigned)(ckey[c] >> 32));
        if (!(lb * 0.999f > ub)) {
          int pos = atomicAdd(qn, 1);
          queue[pos] = (u16)c;
        }
      }
    }
    __syncthreads();
    // Phase B: cooperative refine (half-wave per chunk)
    {
      const int Q = (it == 1) ? NCH : *qn;
      const bool first = (it == 1);
      for (int t = h; t < Q; t += 8) {
        int c = first ? t : (int)queue[t];
        int gidx = c * CHSZ + sub;
        float4 p = SP[gidx];
        float ddo = first ? 1e10f : DD[gidx];
        float dx = __fsub_rn(p.x, cx);
        float dy = __fsub_rn(p.y, cy);
        float dz = __fsub_rn(p.z, cz);
        float d = __fadd_rn(__fadd_rn(__fmul_rn(dx, dx), __fmul_rn(dy, dy)), __fmul_rn(dz, dz));
        float nd = fminf(ddo, d);
        DD[gidx] = nd;
        u64 key = ((u64)__float_as_uint(nd) << 32) |
                  (u64)(0xFFFFFFFFu - (unsigned)__float_as_uint(p.w));
        float bx = p.x, by = p.y, bz = p.z;
#pragma unroll
        for (int off = 16; off; off >>= 1) {
          u64 ok = __shfl_down(key, (unsigned)off);
          float ox = __shfl_down(bx, (unsigned)off);
          float oy = __shfl_down(by, (unsigned)off);
          float oz = __shfl_down(bz, (unsigned)off);
          if (ok > key) { key = ok; bx = ox; by = oy; bz = oz; }
        }
        if (sub == 0) {
          ckey[c] = key;
          cxyz[c * 3 + 0] = bx; cxyz[c * 3 + 1] = by; cxyz[c * 3 + 2] = bz;
        }
      }
    }
    __syncthreads();
    // Phase C: argmax over 2048 exact chunk keys
    {
      u64 key = 0ull; int cid = 0;
#pragma unroll
      for (int i = 0; i < 8; ++i) {
        int c = tid + 256 * i;
        u64 k = ckey[c];
        if (k > key) { key = k; cid = c; }
      }
#pragma unroll
      for (int off = 32; off; off >>= 1) {
        u64 ok = __shfl_down(key, (unsigned)off);
        int oc = __shfl_down(cid, (unsigned)off);
        if (ok > key) { key = ok; cid = oc; }
      }
      if (lane == 0) { warr_key[wave] = key; warr_cid[wave] = cid; }
    }
    __syncthreads();
    // Phase D: final reduce, publish
    if (tid == 0) {
      u64 key = warr_key[0]; int cid = warr_cid[0];
#pragma unroll
      for (int i = 1; i < 4; ++i)
        if (warr_key[i] > key) { key = warr_key[i]; cid = warr_cid[i]; }
      float wx = cxyz[cid * 3 + 0], wy = cxyz[cid * 3 + 1], wz = cxyz[cid * 3 + 2];
      *wslot = make_float4(wx, wy, wz, 0.f);
      u64 tg = (unsigned)(it + 1);
      __hip_atomic_store(cl + (size_t)it * 16 + 0, ((u64)__float_as_uint(wx) << 32) | tg, __ATOMIC_RELAXED, __HIP_MEMORY_SCOPE_AGENT);
      __hip_atomic_store(cl + (size_t)it * 16 + 1, ((u64)__float_as_uint(wy) << 32) | tg, __ATOMIC_RELAXED, __HIP_MEMORY_SCOPE_AGENT);
      __hip_atomic_store(cl + (size_t)it * 16 + 2, ((u64)__float_as_uint(wz) << 32) | tg, __ATOMIC_RELAXED, __HIP_MEMORY_SCOPE_AGENT);
      outC[((size_t)b * kG + it) * 3 + 0] = wx;
      outC[((size_t)b * kG + it) * 3 + 1] = wy;
      outC[((size_t)b * kG + it) * 3 + 2] = wz;
      *qn = 0;
    }
    __syncthreads();
    float4 wc = *wslot;
    cx = wc.x; cy = wc.y; cz = wc.z;
  }
}

// =====================  fused kernel  =====================
__global__ __launch_bounds__(256, 2) void k_fused(
    const float* __restrict__ xyz, const float* __restrict__ color,
    float* __restrict__ outC, float* __restrict__ outE,
    u64* __restrict__ cline, uint32_t* __restrict__ grdy,
    uint32_t* __restrict__ cstart, float4* __restrict__ sorted,
    float* __restrict__ dd_g,
    const _Float16* __restrict__ sw1, const _Float16* __restrict__ sw2,
    const _Float16* __restrict__ sw3, const _Float16* __restrict__ sw4,
    const float* __restrict__ wpt,
    const float* __restrict__ b1, const float* __restrict__ b2,
    const float* __restrict__ b3, const float* __restrict__ b4,
    const float* __restrict__ bp) {
  __shared__ __align__(16) char smem[69760];
  const int bi = blockIdx.x;
  if (bi < NFPS) {
    fps_block(xyz, outC, cline, grdy, cstart, sorted, dd_g, bi, smem);
    return;
  }

  // ---------------- worker ----------------
  const int wj = bi - NFPS;
  const int tid = threadIdx.x;
  const int wave = tid >> 6, lane = tid & 63;
  __shared__ int nC;
  __shared__ float4 spc;
  u64* cand = (u64*)smem;

  // one-time acquire handshake: grid data ready for all batches
  if (tid < 64) {
    long bail = 0;
    for (;;) {
      uint32_t g = 1u;
      if (lane < kB)
        g = __hip_atomic_load(grdy + lane, __ATOMIC_ACQUIRE, __HIP_MEMORY_SCOPE_AGENT);
      if (__all(g == 1u)) break;
      __builtin_amdgcn_s_sleep(64);
      if (++bail > 50000000L) break;
    }
  }
  __syncthreads();

  for (int j = wj; j < kB * kG; j += NWORK) {
    const int it = j >> 2, b = j & 3;
    // wait for center (self-validating words; 1 reader, 1 writer per line)
    if (tid < 64) {
      const u64* e = cline + ((size_t)b * kG + it) * 16;
      u64 v = 0; long bail = 0;
      for (;;) {
        if (lane < 3)
          v = __hip_atomic_load(e + lane, __ATOMIC_RELAXED, __HIP_MEMORY_SCOPE_AGENT);
        bool ok = (lane >= 3) || ((unsigned)v == (unsigned)(it + 1));
        if (__all(ok)) break;
        __builtin_amdgcn_s_sleep(8);
        if (++bail > 100000000L) break;
      }
      u64 v0 = __shfl(v, 0), v1 = __shfl(v, 1), v2 = __shfl(v, 2);
      if (tid == 0)
        spc = make_float4(__uint_as_float((unsigned)(v0 >> 32)),
                          __uint_as_float((unsigned)(v1 >> 32)),
                          __uint_as_float((unsigned)(v2 >> 32)), 0.f);
    }
    __syncthreads();
    const float cx = spc.x, cy = spc.y, cz = spc.z;

    // ---- KNN (expanding box + exact re-rank + bitonic) ----
    const float nc = __fadd_rn(__fadd_rn(__fmul_rn(cx, cx), __fmul_rn(cy, cy)), __fmul_rn(cz, cz));
    const float4* SPb = sorted + (size_t)b * kN;
    const uint32_t* CS = cstart + (size_t)b * (NCELL + 1);
    const int ccx = cellof(cx), ccy = cellof(cy), ccz = cellof(cz);
    if (tid == 0) nC = 0;
    __syncthreads();
    int plox = 1, phix = 0, ploy = 1, phiy = 0, ploz = 1, phiz = 0;
    for (int r = 1; r <= GRD; ++r) {
      int lox = max(0, ccx - r), hix = min(GRD - 1, ccx + r);
      int loy = max(0, ccy - r), hiy = min(GRD - 1, ccy + r);
      int loz = max(0, ccz - r), hiz = min(GRD - 1, ccz + r);
      for (int z = loz; z <= hiz; ++z)
        for (int y = loy; y <= hiy; ++y) {
          bool rowPrev = (r > 1) && (z >= ploz && z <= phiz && y >= ploy && y <= phiy);
          for (int s = 0; s < 2; ++s) {
            int xa, xb;
            if (!rowPrev) { if (s) break; xa = lox; xb = hix; }
            else if (s == 0) { xa = lox; xb = plox - 1; }
            else { xa = phix + 1; xb = hix; }
            if (xa > xb) continue;
            int c0 = (z * GRD + y) * GRD + xa;
            int i0 = CS[c0];
            int i1 = CS[(z * GRD + y) * GRD + xb + 1];
            for (int i = i0 + tid; i < i1; i += 256) {
              float4 pt = SPb[i];
              float npn = __fadd_rn(__fadd_rn(__fmul_rn(pt.x, pt.x), __fmul_rn(pt.y, pt.y)),
                                    __fmul_rn(pt.z, pt.z));
              float dot = __fadd_rn(__fadd_rn(__fmul_rn(cx, pt.x), __fmul_rn(cy, pt.y)),
                                    __fmul_rn(cz, pt.z));
              float sq = __fsub_rn(__fadd_rn(nc, npn), __fmul_rn(2.0f, dot));
              unsigned key = orderable(sq);
              int pos = atomicAdd(&nC, 1);
              if (pos < 8192)
                cand[pos] = ((u64)key << 32) | (unsigned)__float_as_uint(pt.w);
            }
          }
        }
      __syncthreads();
      int n = min(nC, 8192);
      float rc = 1e30f;
      if (lox > 0) rc = fminf(rc, cx - (float)lox * CW);
      if (hix < GRD - 1) rc = fminf(rc, (float)(hix + 1) * CW - cx);
      if (loy > 0) rc = fminf(rc, cy - (float)loy * CW);
      if (hiy < GRD - 1) rc = fminf(rc, (float)(hiy + 1) * CW - cy);
      if (loz > 0) rc = fminf(rc, cz - (float)loz * CW);
      if (hiz < GRD - 1) rc = fminf(rc, (float)(hiz + 1) * CW - cz);
      float r2 = (rc >= 1e29f) ? 3.0e38f : rc * rc * (1.0f - 1e-5f);
      unsigned keyR = orderable(r2);
      bool done = false;
      if (n >= kM) {
        int np2 = 1;
        while (np2 < n) np2 <<= 1;
        for (int i = n + tid; i < np2; i += 256) cand[i] = ~0ull;
        bitonic(cand, np2, tid);
        unsigned k63 = (unsigned)(cand[kM - 1] >> 32);
        done = (k63 <= keyR);
        if (tid == 0) nC = n;
      }
      __syncthreads();
      if (done) break;
      plox = lox; phix = hix; ploy = loy; phiy = hiy; ploz = loz; phiz = hiz;
    }

    // ---- MLP (reuses smem; neighbor indices straight from cand) ----
    uint32_t pidx = 0;
    if (tid < kM) pidx = (uint32_t)(cand[tid] & 0xFFFFFFFFu);
    __syncthreads();
    _Float16* bufA = (_Float16*)smem;
    _Float16* bufB = (_Float16*)(smem + 17408);
    float* maxv = (float*)smem;
    float* psum = (float*)(smem + 2048);
    if (tid < kM) {
      const float* xp = xyz + ((size_t)b * kN + pidx) * 3;
      const float* cp = color + ((size_t)b * kN + pidx) * 3;
      f16x8 v = {};
      v[0] = (_Float16)__fsub_rn(xp[0], cx);
      v[1] = (_Float16)__fsub_rn(xp[1], cy);
      v[2] = (_Float16)__fsub_rn(xp[2], cz);
      v[3] = (_Float16)cp[0];
      v[4] = (_Float16)cp[1];
      v[5] = (_Float16)cp[2];
      f16x8 zf = {};
      *(f16x8*)(bufA + tid * 40 + 0) = v;
      *(f16x8*)(bufA + tid * 40 + 8) = zf;
      *(f16x8*)(bufA + tid * 40 + 16) = zf;
      *(f16x8*)(bufA + tid * 40 + 24) = zf;
    }
    __syncthreads();
    mfma_layer<32, 64, 40, 72>(bufA, bufB, sw1, b1, wave, lane);
    __syncthreads();
    mfma_layer<64, 128, 72, 136>(bufB, bufA, sw2, b2, wave, lane);
    __syncthreads();
    mfma_layer<128, 256, 136, 264>(bufA, bufB, sw3, b3, wave, lane);
    __syncthreads();
    mfma_layer4(bufB, sw4, b4, maxv, wave, lane);
    __syncthreads();
    if (tid < 240) {
      int jj = tid >> 2, q = tid & 3;
      const float* w = wpt + (size_t)jj * 512 + q * 128;
      float s = 0.f;
#pragma unroll 4
      for (int k = 0; k < 128; ++k) s = fmaf(maxv[q * 128 + k], w[k], s);
      psum[tid] = s;
    }
    __syncthreads();
    if (tid < kE) {
      float e = __fadd_rn(__fadd_rn(psum[tid * 4 + 0], psum[tid * 4 + 1]),
                          __fadd_rn(psum[tid * 4 + 2], psum[tid * 4 + 3])) + bp[tid];
      outE[((size_t)b * kG + it) * kE + tid] = e;
    }
    __syncthreads();  // smem reuse fence before next job
  }
}

// =====================  launch  =====================
extern "C" void kernel_launch(void* const* d_in, const int* in_sizes, int n_in,
                              void* d_out, int out_size, void* d_ws, size_t ws_size,
                              hipStream_t stream) {
  (void)in_sizes; (void)n_in; (void)out_size; (void)ws_size;
  const float* xyz = (const float*)d_in[0];
  const float* color = (const float*)d_in[1];
  const float* W1 = (const float*)d_in[2];
  const float* b1 = (const float*)d_in[3];
  const float* W2 = (const float*)d_in[4];
  const float* b2 = (const float*)d_in[5];
  const float* W3 = (const float*)d_in[6];
  const float* b3 = (const float*)d_in[7];
  const float* W4 = (const float*)d_in[8];
  const float* b4 = (const float*)d_in[9];
  const float* Wp = (const float*)d_in[10];
  const float* bp = (const float*)d_in[11];

  char* ws = (char*)d_ws;
  auto cline = (u64*)(ws + OFF_CLINE);
  auto grdy = (uint32_t*)(ws + OFF_GRDY);
  auto cstart = (uint32_t*)(ws + OFF_CSTART);
  auto dd = (float*)(ws + OFF_DD);
  auto sw1 = (_Float16*)(ws + OFF_SW1);
  auto sw2 = (_Float16*)(ws + OFF_SW2);
  auto sw3 = (_Float16*)(ws + OFF_SW3);
  auto sw4 = (_Float16*)(ws + OFF_SW4);
  auto wpt = (float*)(ws + OFF_WPT);
  auto sorted = (float4*)(ws + OFF_SORT);

  float* outE = (float*)d_out;
  float* outC = outE + (size_t)kB * kG * kE;

  k_zero<<<128, 256, 0, stream>>>((uint32_t*)ws, (int)(ZERO_BYTES / 4));
  k_prep<<<256, 256, 0, stream>>>(W1, W2, W3, W4, Wp, sw1, sw2, sw3, sw4, wpt);
  k_fused<<<NBLK, 256, 0, stream>>>(xyz, color, outC, outE, cline, grdy, cstart,
                                    sorted, dd, sw1, sw2, sw3, sw4, wpt,
                                    b1, b2, b3, b4, bp);
}

// Round 4
// 2121.593 us; speedup vs baseline: 3.4229x; 3.4229x over previous
//
#include <hip/hip_runtime.h>
#include <stdint.h>

#define DI __device__ __forceinline__

typedef _Float16 f16x8 __attribute__((ext_vector_type(8)));
typedef float f32x4 __attribute__((ext_vector_type(4)));
typedef unsigned long long u64;

// ---- problem constants ----
constexpr int kB = 4;
constexpr int kN = 65536;
constexpr int kG = 512;   // NUM_GROUP
constexpr int kM = 64;    // GROUP_SIZE
constexpr int kE = 60;    // EMB
constexpr int GRD = 20;   // KNN grid resolution
constexpr int NCELL = GRD * GRD * GRD;
constexpr float CW = 1.0f / 20.0f;

// FPS: 16 blocks per batch, all on ONE XCD (blockIdx % 8 == batch), 256 thr each.
constexpr int FPS_SUB = 16;
constexpr int FPS_TPB = 256;
constexpr int FPS_PT_T = kN / FPS_SUB / FPS_TPB;  // 16 points per thread (registers)
constexpr int NWORK = 448;
constexpr int NBLK = 512;   // 2 blocks/CU, all co-resident

// ---- workspace layout (bytes) ----
// fkey slots per (b,it): FPS_SUB*4 u64, self-validating (intra-XCD sync only):
//   word0 = (dist_bits<<32)|(0xFFFFFFFF-p)  (nonzero once written)
//   word1..3 = (x/y/z bits<<32)|it
// cline per (b,it): 128B line, 3 tagged words (tag=it+1). 1 writer, 1 reader.
constexpr size_t OFF_FKEY   = 0;
constexpr size_t OFF_CLINE  = OFF_FKEY + (size_t)kB * kG * FPS_SUB * 4 * 8;  // 1 MB
constexpr size_t OFF_CCNT   = OFF_CLINE + (size_t)kB * kG * 128;
constexpr size_t OFF_GS     = OFF_CCNT + (size_t)kB * NCELL * 4;   // phase counters
constexpr size_t ZERO_BYTES = OFF_GS + 64;
constexpr size_t OFF_CSTART = (ZERO_BYTES + 255) & ~(size_t)255;   // kB*(NCELL+1) u32
constexpr size_t OFF_CUR    = OFF_CSTART + (size_t)kB * (NCELL + 1) * 4;
constexpr size_t OFF_SW1    = ((OFF_CUR + (size_t)kB * NCELL * 4) + 255) & ~(size_t)255;
constexpr size_t OFF_SW2    = OFF_SW1 + 2048 * 2;
constexpr size_t OFF_SW3    = OFF_SW2 + 8192 * 2;
constexpr size_t OFF_SW4    = OFF_SW3 + 32768 * 2;
constexpr size_t OFF_WPT    = OFF_SW4 + 131072 * 2;
constexpr size_t OFF_SORT   = ((OFF_WPT + 60 * 512 * 4) + 255) & ~(size_t)255; // kB*kN float4

DI int cellof(float x) {
  int c = (int)(x * (float)GRD);
  return min(GRD - 1, max(0, c));
}
DI unsigned orderable(float f) {
  unsigned u = __float_as_uint(f);
  return (u & 0x80000000u) ? ~u : (u | 0x80000000u);
}

// =====================  zero the sync/count region  =====================
__global__ void k_zero(uint32_t* p, int nwords) {
  int i = blockIdx.x * blockDim.x + threadIdx.x;
  int st = gridDim.x * blockDim.x;
  for (; i < nwords; i += st) p[i] = 0u;
}

// =====================  weight prep: B-fragment swizzle (f16) + WpT  =====================
DI void swz(const float* __restrict__ W, _Float16* __restrict__ sw,
            int total, int nks, int Kreal, int N, int i0, int st) {
  for (int i = i0; i < total; i += st) {
    int j = i & 7, lane = (i >> 3) & 63, rest = i >> 9;
    int ks = rest % nks, nt = rest / nks;
    int k = ks * 32 + ((lane >> 4) << 3) + j;
    int n = nt * 16 + (lane & 15);
    sw[i] = (_Float16)((k < Kreal) ? W[k * N + n] : 0.f);
  }
}

__global__ void k_prep(const float* __restrict__ W1, const float* __restrict__ W2,
                       const float* __restrict__ W3, const float* __restrict__ W4,
                       const float* __restrict__ Wp,
                       _Float16* __restrict__ sw1, _Float16* __restrict__ sw2,
                       _Float16* __restrict__ sw3, _Float16* __restrict__ sw4,
                       float* __restrict__ wpt) {
  int i0 = blockIdx.x * blockDim.x + threadIdx.x;
  int st = gridDim.x * blockDim.x;
  swz(W1, sw1, 2048, 1, 6, 64, i0, st);
  swz(W2, sw2, 8192, 2, 64, 128, i0, st);
  swz(W3, sw3, 32768, 4, 128, 256, i0, st);
  swz(W4, sw4, 131072, 8, 256, 512, i0, st);
  for (int i = i0; i < 60 * 512; i += st) { int n = i >> 9, k = i & 511; wpt[i] = Wp[k * 60 + n]; }
}

// =====================  device-wide phase barrier (co-resident workers)  =====================
DI void gbar(uint32_t* ctr, unsigned target) {
  __syncthreads();
  if (threadIdx.x == 0) {
    __hip_atomic_fetch_add(ctr, 1u, __ATOMIC_ACQ_REL, __HIP_MEMORY_SCOPE_AGENT);
    long bail = 0;
    while (__hip_atomic_load(ctr, __ATOMIC_ACQUIRE, __HIP_MEMORY_SCOPE_AGENT) < target) {
      __builtin_amdgcn_s_sleep(32);
      if (++bail > 100000000L) break;
    }
  }
  __syncthreads();
}

// =====================  FPS block (XCD-local sync)  =====================
DI void fps_block(const float* __restrict__ xyz, float* __restrict__ outC,
                  u64* __restrict__ fkey, u64* __restrict__ cline, int b, int sub) {
  __builtin_amdgcn_s_setprio(3);
  const int tid = threadIdx.x;
  const int wave = tid >> 6, lane = tid & 63;
  const float* X = xyz + (size_t)b * kN * 3;
  float px[FPS_PT_T], py[FPS_PT_T], pz[FPS_PT_T], dd[FPS_PT_T];
#pragma unroll
  for (int j = 0; j < FPS_PT_T; ++j) {
    int p = sub * (kN / FPS_SUB) + j * FPS_TPB + tid;
    px[j] = X[3 * p]; py[j] = X[3 * p + 1]; pz[j] = X[3 * p + 2];
    dd[j] = 1e10f;
  }
  float lx = X[0], ly = X[1], lz = X[2];
  u64* cl = cline + (size_t)b * kG * 16;
  if (sub == 0 && tid == 0) {
    outC[(size_t)b * kG * 3 + 0] = lx;
    outC[(size_t)b * kG * 3 + 1] = ly;
    outC[(size_t)b * kG * 3 + 2] = lz;
    u64 tg = 1u;  // tag = it+1 for it=0
    __hip_atomic_store(cl + 0, ((u64)__float_as_uint(lx) << 32) | tg, __ATOMIC_RELAXED, __HIP_MEMORY_SCOPE_AGENT);
    __hip_atomic_store(cl + 1, ((u64)__float_as_uint(ly) << 32) | tg, __ATOMIC_RELAXED, __HIP_MEMORY_SCOPE_AGENT);
    __hip_atomic_store(cl + 2, ((u64)__float_as_uint(lz) << 32) | tg, __ATOMIC_RELAXED, __HIP_MEMORY_SCOPE_AGENT);
  }
  __shared__ u64 s_key[4];
  __shared__ float s_x[4], s_y[4], s_z[4];
  __shared__ float4 sp;
  u64* keyB = fkey + (size_t)b * kG * (FPS_SUB * 4);

  for (int it = 1; it < kG; ++it) {
    float bnd = -1.0f, bx = 0.f, by = 0.f, bz = 0.f;
    int bp = 0;
#pragma unroll
    for (int j = 0; j < FPS_PT_T; ++j) {
      float dx = __fsub_rn(px[j], lx);
      float dy = __fsub_rn(py[j], ly);
      float dz = __fsub_rn(pz[j], lz);
      float d = __fadd_rn(__fadd_rn(__fmul_rn(dx, dx), __fmul_rn(dy, dy)), __fmul_rn(dz, dz));
      float nd = fminf(dd[j], d);
      dd[j] = nd;
      int p = sub * (kN / FPS_SUB) + j * FPS_TPB + tid;
      if (nd > bnd) { bnd = nd; bx = px[j]; by = py[j]; bz = pz[j]; bp = p; }
    }
    u64 best = ((u64)__float_as_uint(bnd) << 32) | (unsigned)(0xFFFFFFFFu - (unsigned)bp);
#pragma unroll
    for (int off = 32; off; off >>= 1) {
      u64 ok = __shfl_down(best, (unsigned)off);
      float ox = __shfl_down(bx, (unsigned)off);
      float oy = __shfl_down(by, (unsigned)off);
      float oz = __shfl_down(bz, (unsigned)off);
      if (ok > best) { best = ok; bx = ox; by = oy; bz = oz; }
    }
    if (lane == 0) { s_key[wave] = best; s_x[wave] = bx; s_y[wave] = by; s_z[wave] = bz; }
    __syncthreads();
    if (wave == 0) {
      int i4 = lane & 3;
      u64 kk = s_key[i4]; float kx = s_x[i4], ky = s_y[i4], kz = s_z[i4];
#pragma unroll
      for (int off = 2; off; off >>= 1) {
        u64 ok = __shfl_down(kk, (unsigned)off);
        float ox = __shfl_down(kx, (unsigned)off);
        float oy = __shfl_down(ky, (unsigned)off);
        float oz = __shfl_down(kz, (unsigned)off);
        if (ok > kk) { kk = ok; kx = ox; ky = oy; kz = oz; }
      }
      u64* slots = keyB + (size_t)it * (FPS_SUB * 4);
      if (lane == 0) {
        u64 tag = (unsigned)it;
        u64* my = slots + sub * 4;
        __hip_atomic_store(my + 1, ((u64)__float_as_uint(kx) << 32) | tag,
                           __ATOMIC_RELAXED, __HIP_MEMORY_SCOPE_AGENT);
        __hip_atomic_store(my + 2, ((u64)__float_as_uint(ky) << 32) | tag,
                           __ATOMIC_RELAXED, __HIP_MEMORY_SCOPE_AGENT);
        __hip_atomic_store(my + 3, ((u64)__float_as_uint(kz) << 32) | tag,
                           __ATOMIC_RELAXED, __HIP_MEMORY_SCOPE_AGENT);
        __hip_atomic_store(my + 0, kk, __ATOMIC_RELAXED, __HIP_MEMORY_SCOPE_AGENT);
      }
      // poll all 16 slots x 4 words with 64 lanes; XCD-local L2 -> tight loop
      u64 v = 0; bool okp; long bail = 0;
      do {
        v = __hip_atomic_load(slots + lane, __ATOMIC_RELAXED, __HIP_MEMORY_SCOPE_AGENT);
        okp = (lane & 3) ? ((unsigned)v == (unsigned)it) : (v != 0ull);
      } while (!__all(okp) && ++bail < 100000000L);
      u64 key = ((lane & 3) == 0) ? v : 0ull;
      int slot = lane >> 2;
#pragma unroll
      for (int off = 32; off; off >>= 1) {
        u64 ok = __shfl_down(key, (unsigned)off);
        int os = __shfl_down(slot, (unsigned)off);
        if (ok > key) { key = ok; slot = os; }
      }
      slot = __shfl(slot, 0);
      u64 vx = __shfl(v, slot * 4 + 1);
      u64 vy = __shfl(v, slot * 4 + 2);
      u64 vz = __shfl(v, slot * 4 + 3);
      if (lane == 0) {
        float wxc = __uint_as_float((unsigned)(vx >> 32));
        float wyc = __uint_as_float((unsigned)(vy >> 32));
        float wzc = __uint_as_float((unsigned)(vz >> 32));
        sp = make_float4(wxc, wyc, wzc, 0.f);
        if (sub == 0) {
          outC[((size_t)b * kG + it) * 3 + 0] = wxc;
          outC[((size_t)b * kG + it) * 3 + 1] = wyc;
          outC[((size_t)b * kG + it) * 3 + 2] = wzc;
          u64 tg = (unsigned)(it + 1);
          u64* e = cl + (size_t)it * 16;
          __hip_atomic_store(e + 0, ((u64)__float_as_uint(wxc) << 32) | tg, __ATOMIC_RELAXED, __HIP_MEMORY_SCOPE_AGENT);
          __hip_atomic_store(e + 1, ((u64)__float_as_uint(wyc) << 32) | tg, __ATOMIC_RELAXED, __HIP_MEMORY_SCOPE_AGENT);
          __hip_atomic_store(e + 2, ((u64)__float_as_uint(wzc) << 32) | tg, __ATOMIC_RELAXED, __HIP_MEMORY_SCOPE_AGENT);
        }
      }
    }
    __syncthreads();
    lx = sp.x; ly = sp.y; lz = sp.z;
  }
}

// =====================  bitonic sort (shared, 256 threads)  =====================
DI void bitonic(u64* a, int n, int tid) {
  for (int k = 2; k <= n; k <<= 1)
    for (int j = k >> 1; j > 0; j >>= 1) {
      __syncthreads();
      for (int i = tid; i < n; i += 256) {
        int ix = i ^ j;
        if (ix > i) {
          u64 x = a[i], y = a[ix];
          bool up = ((i & k) == 0);
          if ((x > y) == up) { a[i] = y; a[ix] = x; }
        }
      }
    }
  __syncthreads();
}

// =====================  MLP layers (f16 MFMA)  =====================
template <int Kdim, int Ndim, int SIN, int SOUT>
DI void mfma_layer(const _Float16* __restrict__ Xin, _Float16* __restrict__ Xout,
                   const _Float16* __restrict__ Wsw, const float* __restrict__ bias,
                   int wave, int lane) {
  constexpr int NKS = Kdim / 32;
  constexpr int NTW = Ndim / 64;
  constexpr int CH = (NTW < 4) ? NTW : 4;
  const int quad = lane >> 4, l16 = lane & 15;
  for (int c0 = 0; c0 < NTW; c0 += CH) {
    f32x4 acc[CH][4];
#pragma unroll
    for (int nt = 0; nt < CH; ++nt) {
      float bv = bias[wave * (Ndim / 4) + (c0 + nt) * 16 + l16];
#pragma unroll
      for (int m = 0; m < 4; ++m) acc[nt][m] = {bv, bv, bv, bv};
    }
#pragma unroll
    for (int ks = 0; ks < NKS; ++ks) {
      f16x8 af[4];
#pragma unroll
      for (int m = 0; m < 4; ++m)
        af[m] = *(const f16x8*)(Xin + (m * 16 + l16) * SIN + ks * 32 + quad * 8);
#pragma unroll
      for (int nt = 0; nt < CH; ++nt) {
        int ntg = wave * NTW + c0 + nt;
        f16x8 bf = *(const f16x8*)(Wsw + ((size_t)(ntg * NKS + ks) * 64 + lane) * 8);
#pragma unroll
        for (int m = 0; m < 4; ++m)
          acc[nt][m] = __builtin_amdgcn_mfma_f32_16x16x32_f16(af[m], bf, acc[nt][m], 0, 0, 0);
      }
    }
#pragma unroll
    for (int nt = 0; nt < CH; ++nt) {
      int col = wave * (Ndim / 4) + (c0 + nt) * 16 + l16;
#pragma unroll
      for (int m = 0; m < 4; ++m)
#pragma unroll
        for (int r = 0; r < 4; ++r) {
          int row = m * 16 + quad * 4 + r;
          Xout[row * SOUT + col] = (_Float16)fmaxf(acc[nt][m][r], 0.f);
        }
    }
  }
}

DI void mfma_layer4(const _Float16* __restrict__ Xin, const _Float16* __restrict__ Wsw,
                    const float* __restrict__ bias, float* __restrict__ maxv,
                    int wave, int lane) {
  constexpr int SIN = 264, NKS = 8, NTW = 8, CH = 4;
  const int quad = lane >> 4, l16 = lane & 15;
  for (int c0 = 0; c0 < NTW; c0 += CH) {
    f32x4 acc[CH][4];
#pragma unroll
    for (int nt = 0; nt < CH; ++nt) {
      float bv = bias[wave * 128 + (c0 + nt) * 16 + l16];
#pragma unroll
      for (int m = 0; m < 4; ++m) acc[nt][m] = {bv, bv, bv, bv};
    }
#pragma unroll
    for (int ks = 0; ks < NKS; ++ks) {
      f16x8 af[4];
#pragma unroll
      for (int m = 0; m < 4; ++m)
        af[m] = *(const f16x8*)(Xin + (m * 16 + l16) * SIN + ks * 32 + quad * 8);
#pragma unroll
      for (int nt = 0; nt < CH; ++nt) {
        int ntg = wave * NTW + c0 + nt;
        f16x8 bf = *(const f16x8*)(Wsw + ((size_t)(ntg * NKS + ks) * 64 + lane) * 8);
#pragma unroll
        for (int m = 0; m < 4; ++m)
          acc[nt][m] = __builtin_amdgcn_mfma_f32_16x16x32_f16(af[m], bf, acc[nt][m], 0, 0, 0);
      }
    }
#pragma unroll
    for (int nt = 0; nt < CH; ++nt) {
      float mx = 0.f;  // relu folded into max
#pragma unroll
      for (int m = 0; m < 4; ++m)
#pragma unroll
        for (int r = 0; r < 4; ++r) mx = fmaxf(mx, acc[nt][m][r]);
      mx = fmaxf(mx, __shfl_xor(mx, 16, 64));
      mx = fmaxf(mx, __shfl_xor(mx, 32, 64));
      if (quad == 0) maxv[wave * 128 + (c0 + nt) * 16 + l16] = mx;
    }
  }
}

// =====================  fused kernel  =====================
__global__ __launch_bounds__(256, 2) void k_fused(
    const float* __restrict__ xyz, const float* __restrict__ color,
    float* __restrict__ outC, float* __restrict__ outE,
    u64* __restrict__ fkey, u64* __restrict__ cline,
    uint32_t* __restrict__ ccnt, uint32_t* __restrict__ cstart,
    uint32_t* __restrict__ cur, float4* __restrict__ sorted,
    uint32_t* __restrict__ gs,
    const _Float16* __restrict__ sw1, const _Float16* __restrict__ sw2,
    const _Float16* __restrict__ sw3, const _Float16* __restrict__ sw4,
    const float* __restrict__ wpt,
    const float* __restrict__ b1, const float* __restrict__ b2,
    const float* __restrict__ b3, const float* __restrict__ b4,
    const float* __restrict__ bp) {
  const int bi = blockIdx.x;
  // FPS: blocks bi<128 with (bi&7)<kB  ->  batch b=bi&7 on XCD b, sub=bi>>3
  if (bi < 128 && (bi & 7) < kB) {
    fps_block(xyz, outC, fkey, cline, bi & 7, bi >> 3);
    return;
  }

  // ---------------- worker block ----------------
  const int wj = (bi < 128) ? ((bi >> 3) * 4 + ((bi & 7) - kB)) : (64 + (bi - 128));
  const int tid = threadIdx.x;
  const int wave = tid >> 6, lane = tid & 63;
  __shared__ __align__(16) char smem[65536];   // cand (64KB) ∪ {bufA,bufB,maxv,psum}
  __shared__ int nC;
  __shared__ float4 spc;
  __shared__ uint32_t s_part[256];
  u64* cand = (u64*)smem;

  // ---- grid build (overlapped with early FPS rounds) ----
  for (int i = wj * 256 + tid; i < kB * kN; i += NWORK * 256) {
    int b = i >> 16, p = i & (kN - 1);
    const float* q = xyz + ((size_t)b * kN + p) * 3;
    int cid = (cellof(q[2]) * GRD + cellof(q[1])) * GRD + cellof(q[0]);
    atomicAdd(&ccnt[b * NCELL + cid], 1u);
  }
  gbar(gs + 0, NWORK);
  if (wj < kB) {
    int b = wj;
    const uint32_t* cc = ccnt + (size_t)b * NCELL;
    uint32_t* cs = cstart + (size_t)b * (NCELL + 1);
    uint32_t* cu = cur + (size_t)b * NCELL;
    const int chunk = 32;
    int c0 = tid * chunk;
    uint32_t s = 0;
    for (int i = 0; i < chunk; ++i) { int c = c0 + i; if (c < NCELL) s += cc[c]; }
    s_part[tid] = s;
    __syncthreads();
    for (int off = 1; off < 256; off <<= 1) {
      uint32_t add = (tid >= off) ? s_part[tid - off] : 0u;
      __syncthreads();
      s_part[tid] += add;
      __syncthreads();
    }
    uint32_t run = s_part[tid] - s;
    for (int i = 0; i < chunk; ++i) {
      int c = c0 + i;
      if (c < NCELL) { cs[c] = run; cu[c] = run; run += cc[c]; }
    }
    if (tid == 255) cs[NCELL] = run;
  }
  gbar(gs + 1, NWORK);
  for (int i = wj * 256 + tid; i < kB * kN; i += NWORK * 256) {
    int b = i >> 16, p = i & (kN - 1);
    const float* q = xyz + ((size_t)b * kN + p) * 3;
    float x = q[0], y = q[1], z = q[2];
    int cid = (cellof(z) * GRD + cellof(y)) * GRD + cellof(x);
    uint32_t pos = atomicAdd(&cur[b * NCELL + cid], 1u);
    sorted[(size_t)b * kN + pos] = make_float4(x, y, z, __uint_as_float((unsigned)p));
  }
  gbar(gs + 2, NWORK);

  // ---- consume groups in production order: job j = it*4 + b ----
  for (int j = wj; j < kB * kG; j += NWORK) {
    const int it = j >> 2, b = j & 3;
    // wait for center (self-validating tagged words; 1 writer, 1 reader)
    if (tid < 64) {
      const u64* e = cline + ((size_t)b * kG + it) * 16;
      u64 v = 0; long bail = 0;
      for (;;) {
        if (lane < 3)
          v = __hip_atomic_load(e + lane, __ATOMIC_RELAXED, __HIP_MEMORY_SCOPE_AGENT);
        bool ok = (lane >= 3) || ((unsigned)v == (unsigned)(it + 1));
        if (__all(ok)) break;
        __builtin_amdgcn_s_sleep(8);
        if (++bail > 100000000L) break;
      }
      u64 v0 = __shfl(v, 0), v1 = __shfl(v, 1), v2 = __shfl(v, 2);
      if (tid == 0)
        spc = make_float4(__uint_as_float((unsigned)(v0 >> 32)),
                          __uint_as_float((unsigned)(v1 >> 32)),
                          __uint_as_float((unsigned)(v2 >> 32)), 0.f);
    }
    __syncthreads();
    const float cx = spc.x, cy = spc.y, cz = spc.z;

    // ---- KNN (expanding box + exact re-rank + bitonic) ----
    const float nc = __fadd_rn(__fadd_rn(__fmul_rn(cx, cx), __fmul_rn(cy, cy)), __fmul_rn(cz, cz));
    const float4* SPb = sorted + (size_t)b * kN;
    const uint32_t* CS = cstart + (size_t)b * (NCELL + 1);
    const int ccx = cellof(cx), ccy = cellof(cy), ccz = cellof(cz);
    if (tid == 0) nC = 0;
    __syncthreads();
    int plox = 1, phix = 0, ploy = 1, phiy = 0, ploz = 1, phiz = 0;
    for (int r = 1; r <= GRD; ++r) {
      int lox = max(0, ccx - r), hix = min(GRD - 1, ccx + r);
      int loy = max(0, ccy - r), hiy = min(GRD - 1, ccy + r);
      int loz = max(0, ccz - r), hiz = min(GRD - 1, ccz + r);
      for (int z = loz; z <= hiz; ++z)
        for (int y = loy; y <= hiy; ++y) {
          bool rowPrev = (r > 1) && (z >= ploz && z <= phiz && y >= ploy && y <= phiy);
          for (int s = 0; s < 2; ++s) {
            int xa, xb;
            if (!rowPrev) { if (s) break; xa = lox; xb = hix; }
            else if (s == 0) { xa = lox; xb = plox - 1; }
            else { xa = phix + 1; xb = hix; }
            if (xa > xb) continue;
            int c0 = (z * GRD + y) * GRD + xa;
            int i0 = CS[c0];
            int i1 = CS[(z * GRD + y) * GRD + xb + 1];
            for (int i = i0 + tid; i < i1; i += 256) {
              float4 pt = SPb[i];
              float npn = __fadd_rn(__fadd_rn(__fmul_rn(pt.x, pt.x), __fmul_rn(pt.y, pt.y)),
                                    __fmul_rn(pt.z, pt.z));
              float dot = __fadd_rn(__fadd_rn(__fmul_rn(cx, pt.x), __fmul_rn(cy, pt.y)),
                                    __fmul_rn(cz, pt.z));
              float sq = __fsub_rn(__fadd_rn(nc, npn), __fmul_rn(2.0f, dot));
              unsigned key = orderable(sq);
              int pos = atomicAdd(&nC, 1);
              if (pos < 8192)
                cand[pos] = ((u64)key << 32) | (unsigned)__float_as_uint(pt.w);
            }
          }
        }
      __syncthreads();
      int n = min(nC, 8192);
      float rc = 1e30f;
      if (lox > 0) rc = fminf(rc, cx - (float)lox * CW);
      if (hix < GRD - 1) rc = fminf(rc, (float)(hix + 1) * CW - cx);
      if (loy > 0) rc = fminf(rc, cy - (float)loy * CW);
      if (hiy < GRD - 1) rc = fminf(rc, (float)(hiy + 1) * CW - cy);
      if (loz > 0) rc = fminf(rc, cz - (float)loz * CW);
      if (hiz < GRD - 1) rc = fminf(rc, (float)(hiz + 1) * CW - cz);
      float r2 = (rc >= 1e29f) ? 3.0e38f : rc * rc * (1.0f - 1e-5f);
      unsigned keyR = orderable(r2);
      bool done = false;
      if (n >= kM) {
        int np2 = 1;
        while (np2 < n) np2 <<= 1;
        for (int i = n + tid; i < np2; i += 256) cand[i] = ~0ull;
        bitonic(cand, np2, tid);
        unsigned k63 = (unsigned)(cand[kM - 1] >> 32);
        done = (k63 <= keyR);
        if (tid == 0) nC = n;
      }
      __syncthreads();
      if (done) break;
      plox = lox; phix = hix; ploy = loy; phiy = hiy; ploz = loz; phiz = hiz;
    }

    // ---- MLP (reuses smem; neighbor indices straight from cand) ----
    uint32_t pidx = 0;
    if (tid < kM) pidx = (uint32_t)(cand[tid] & 0xFFFFFFFFu);
    __syncthreads();
    _Float16* bufA = (_Float16*)smem;
    _Float16* bufB = (_Float16*)(smem + 17408);
    float* maxv = (float*)smem;
    float* psum = (float*)(smem + 2048);
    if (tid < kM) {
      const float* xp = xyz + ((size_t)b * kN + pidx) * 3;
      const float* cp = color + ((size_t)b * kN + pidx) * 3;
      f16x8 v = {};
      v[0] = (_Float16)__fsub_rn(xp[0], cx);
      v[1] = (_Float16)__fsub_rn(xp[1], cy);
      v[2] = (_Float16)__fsub_rn(xp[2], cz);
      v[3] = (_Float16)cp[0];
      v[4] = (_Float16)cp[1];
      v[5] = (_Float16)cp[2];
      f16x8 zf = {};
      *(f16x8*)(bufA + tid * 40 + 0) = v;
      *(f16x8*)(bufA + tid * 40 + 8) = zf;
      *(f16x8*)(bufA + tid * 40 + 16) = zf;
      *(f16x8*)(bufA + tid * 40 + 24) = zf;
    }
    __syncthreads();
    mfma_layer<32, 64, 40, 72>(bufA, bufB, sw1, b1, wave, lane);
    __syncthreads();
    mfma_layer<64, 128, 72, 136>(bufB, bufA, sw2, b2, wave, lane);
    __syncthreads();
    mfma_layer<128, 256, 136, 264>(bufA, bufB, sw3, b3, wave, lane);
    __syncthreads();
    mfma_layer4(bufB, sw4, b4, maxv, wave, lane);
    __syncthreads();
    if (tid < 240) {
      int jj = tid >> 2, q = tid & 3;
      const float* w = wpt + (size_t)jj * 512 + q * 128;
      float s = 0.f;
#pragma unroll 4
      for (int k = 0; k < 128; ++k) s = fmaf(maxv[q * 128 + k], w[k], s);
      psum[tid] = s;
    }
    __syncthreads();
    if (tid < kE) {
      float e = __fadd_rn(__fadd_rn(psum[tid * 4 + 0], psum[tid * 4 + 1]),
                          __fadd_rn(psum[tid * 4 + 2], psum[tid * 4 + 3])) + bp[tid];
      outE[((size_t)b * kG + it) * kE + tid] = e;
    }
    __syncthreads();  // smem reuse fence before next job
  }
}

// =====================  launch  =====================
extern "C" void kernel_launch(void* const* d_in, const int* in_sizes, int n_in,
                              void* d_out, int out_size, void* d_ws, size_t ws_size,
                              hipStream_t stream) {
  (void)in_sizes; (void)n_in; (void)out_size; (void)ws_size;
  const float* xyz = (const float*)d_in[0];
  const float* color = (const float*)d_in[1];
  const float* W1 = (const float*)d_in[2];
  const float* b1 = (const float*)d_in[3];
  const float* W2 = (const float*)d_in[4];
  const float* b2 = (const float*)d_in[5];
  const float* W3 = (const float*)d_in[6];
  const float* b3 = (const float*)d_in[7];
  const float* W4 = (const float*)d_in[8];
  const float* b4 = (const float*)d_in[9];
  const float* Wp = (const float*)d_in[10];
  const float* bp = (const float*)d_in[11];

  char* ws = (char*)d_ws;
  auto fkey = (u64*)(ws + OFF_FKEY);
  auto cline = (u64*)(ws + OFF_CLINE);
  auto ccnt = (uint32_t*)(ws + OFF_CCNT);
  auto gs = (uint32_t*)(ws + OFF_GS);
  auto cstart = (uint32_t*)(ws + OFF_CSTART);
  auto cur = (uint32_t*)(ws + OFF_CUR);
  auto sw1 = (_Float16*)(ws + OFF_SW1);
  auto sw2 = (_Float16*)(ws + OFF_SW2);
  auto sw3 = (_Float16*)(ws + OFF_SW3);
  auto sw4 = (_Float16*)(ws + OFF_SW4);
  auto wpt = (float*)(ws + OFF_WPT);
  auto sorted = (float4*)(ws + OFF_SORT);

  float* outE = (float*)d_out;
  float* outC = outE + (size_t)kB * kG * kE;

  k_zero<<<256, 256, 0, stream>>>((uint32_t*)ws, (int)(ZERO_BYTES / 4));
  k_prep<<<256, 256, 0, stream>>>(W1, W2, W3, W4, Wp, sw1, sw2, sw3, sw4, wpt);
  k_fused<<<NBLK, 256, 0, stream>>>(xyz, color, outC, outE, fkey, cline, ccnt, cstart,
                                    cur, sorted, gs, sw1, sw2, sw3, sw4, wpt,
                                    b1, b2, b3, b4, bp);
}